// Round 6
// baseline (266.067 us; speedup 1.0000x reference)
//
#include <hip/hip_runtime.h>
#include <hip/hip_bf16.h>

typedef __bf16 bf16;
typedef __attribute__((ext_vector_type(8))) __bf16 bf16x8;
typedef __attribute__((ext_vector_type(4))) float floatx4;

// async global->LDS, 16B per lane. LDS dest is wave-uniform base + lane*16 (fixed by HW);
// we swizzle the GLOBAL source chunk so LDS frag reads are conflict-free (R5: conflicts 4.2M -> 0).
__device__ __forceinline__ void gl_lds16(const bf16* g, bf16* l) {
    __builtin_amdgcn_global_load_lds(
        (const __attribute__((address_space(1))) unsigned int*)g,
        (__attribute__((address_space(3))) unsigned int*)l,
        16, 0, 0);
}

// ---------------------------------------------------------------- x fp32 [R,C] -> xb bf16 [R,C] AND xt bf16 [C,R]
__global__ __launch_bounds__(256) void cast_both(const float* __restrict__ in,
                                                 bf16* __restrict__ outn,
                                                 bf16* __restrict__ outt,
                                                 int R, int C) {
    __shared__ float tile[32][33];
    const long long bz = blockIdx.z;
    in   += bz * (long long)R * C;
    outn += bz * (long long)R * C;
    outt += bz * (long long)R * C;
    const int r0 = blockIdx.x * 32, c0 = blockIdx.y * 32;
    const int tx = threadIdx.x & 31, ty = threadIdx.x >> 5;
#pragma unroll
    for (int i = 0; i < 32; i += 8) {
        float v = in[(long long)(r0 + ty + i) * C + (c0 + tx)];
        tile[ty + i][tx] = v;
        outn[(long long)(r0 + ty + i) * C + (c0 + tx)] = (bf16)v;
    }
    __syncthreads();
#pragma unroll
    for (int i = 0; i < 32; i += 8)
        outt[(long long)(c0 + ty + i) * R + (r0 + tx)] = (bf16)tile[tx][ty + i];
}

// ---------------------------------------------------------------- fp32 [R,C] -> bf16 [C,R] (for W)
__global__ __launch_bounds__(256) void cast_transpose(const float* __restrict__ in,
                                                      bf16* __restrict__ out,
                                                      int R, int C) {
    __shared__ float tile[32][33];
    const int r0 = blockIdx.x * 32, c0 = blockIdx.y * 32;
    const int tx = threadIdx.x & 31, ty = threadIdx.x >> 5;
#pragma unroll
    for (int i = 0; i < 32; i += 8)
        tile[ty + i][tx] = in[(long long)(r0 + ty + i) * C + (c0 + tx)];
    __syncthreads();
#pragma unroll
    for (int i = 0; i < 32; i += 8)
        out[(long long)(c0 + ty + i) * R + (r0 + tx)] = (bf16)tile[tx][ty + i];
}

__device__ __forceinline__ float fast_tanh(float v) {
    float e = __expf(2.0f * v);
    return 1.0f - 2.0f / (e + 1.0f);
}

// ---------------------------------------------------------------- 256(M)x128(N)-block NT GEMM, BK=64
// C[M,N] = A[M,K] * B[N,K]^T; row-major bf16; K%64==0, M%256==0, N%128==0.
// 4 waves, each owns a 128x64 tile (8x4 of 16x16): LDS bytes/FLOP 25% lower than 64x64 wave
// tiles (LDS-BW bound per R5 counters), 2x MFMA per barrier drain.
// MODE 0: store bf16. MODE 1: store bf16 exp(tanh(v)) + fp32 rowsum atomics. MODE 2: fp32 v/rowsum.
template <int MODE>
__global__ __launch_bounds__(256) void gemm256(const bf16* __restrict__ A,
                                               const bf16* __restrict__ Bm,
                                               void* __restrict__ Cout,
                                               float* __restrict__ rowsum,
                                               int M, int N, int K,
                                               long long batchA, long long batchB,
                                               long long batchC, long long batchR) {
    const long long bz = blockIdx.z;
    A  += bz * batchA;
    Bm += bz * batchB;

    __shared__ bf16 As[256 * 64];   // 32 KB
    __shared__ bf16 Bs[128 * 64];   // 16 KB
    __shared__ float rs[256];       // MODE 2

    const int t    = threadIdx.x;
    const int lane = t & 63;
    const int wave = t >> 6;
    const int quad = lane >> 4;
    const int l16  = lane & 15;

    const int m0 = blockIdx.x * 256;
    const int n0 = blockIdx.y * 128;
    const int wm = (wave >> 1) * 128;   // wave tile: 128 rows
    const int wn = (wave & 1) * 64;     //            64 cols

    floatx4 acc[8][4] = {};

    // staging: rows of 64 bf16 = 8 chunks of 16B. LDS slot (r, cl) holds global (r, cl ^ (r&7)).
    const int ra = t >> 3;                         // 0..31
    const int ca = (((t & 7) ^ (ra & 7))) * 8;     // swizzled global col
    const long long rstep = 32LL * K;
    const bf16* Abase = A + (long long)(m0 + ra) * K + ca;
    const bf16* Bbase = Bm + (long long)(n0 + ra) * K + ca;

    // frag-read chunk offsets: ((s*4+quad) ^ (l16&7)) * 8
    const int cq0 = ((quad) ^ (l16 & 7)) * 8;
    const int cq1 = ((4 + quad) ^ (l16 & 7)) * 8;

    for (int k0 = 0; k0 < K; k0 += 64) {
#pragma unroll
        for (int i = 0; i < 8; ++i)    // A: 256 rows
            gl_lds16(Abase + k0 + i * rstep, &As[(t + 256 * i) * 8]);
#pragma unroll
        for (int i = 0; i < 4; ++i)    // B: 128 rows
            gl_lds16(Bbase + k0 + i * rstep, &Bs[(t + 256 * i) * 8]);
        __syncthreads();

#pragma unroll
        for (int s = 0; s < 2; ++s) {
            const int cq = s ? cq1 : cq0;
            bf16x8 af[8], bfr[4];
#pragma unroll
            for (int i = 0; i < 8; ++i)
                af[i] = *(const bf16x8*)(&As[(wm + i * 16 + l16) * 64 + cq]);
#pragma unroll
            for (int j = 0; j < 4; ++j)
                bfr[j] = *(const bf16x8*)(&Bs[(wn + j * 16 + l16) * 64 + cq]);
#pragma unroll
            for (int i = 0; i < 8; ++i)
#pragma unroll
                for (int j = 0; j < 4; ++j)
                    acc[i][j] = __builtin_amdgcn_mfma_f32_16x16x32_bf16(af[i], bfr[j], acc[i][j], 0, 0, 0);
        }
        __syncthreads();
    }

    if (MODE == 2) {
        rs[t] = rowsum[bz * batchR + m0 + t];
        __syncthreads();
        float* Og = (float*)Cout + bz * batchC;
#pragma unroll
        for (int i = 0; i < 8; ++i)
#pragma unroll
            for (int r = 0; r < 4; ++r) {
                int rl = wm + i * 16 + quad * 4 + r;
                float inv = 1.0f / rs[rl];
                long long row = m0 + rl;
#pragma unroll
                for (int j = 0; j < 4; ++j)
                    Og[row * (long long)N + (n0 + wn + j * 16 + l16)] = acc[i][j][r] * inv;
            }
    } else {
        bf16* Cg = (bf16*)Cout + bz * batchC;
#pragma unroll
        for (int i = 0; i < 8; ++i)
#pragma unroll
            for (int r = 0; r < 4; ++r) {
                long long row = m0 + wm + i * 16 + quad * 4 + r;
                float sum = 0.f;
#pragma unroll
                for (int j = 0; j < 4; ++j) {
                    float v = acc[i][j][r];
                    if (MODE == 1) { v = __expf(fast_tanh(v)); sum += v; }
                    Cg[row * (long long)N + (n0 + wn + j * 16 + l16)] = (bf16)v;
                }
                if (MODE == 1) {
#pragma unroll
                    for (int msk = 1; msk < 16; msk <<= 1) sum += __shfl_xor(sum, msk);
                    if (l16 == 0) atomicAdd(&rowsum[bz * batchR + row], sum);
                }
            }
    }
}

// ----------------------------------------------------------------
extern "C" void kernel_launch(void* const* d_in, const int* in_sizes, int n_in,
                              void* d_out, int out_size, void* d_ws, size_t ws_size,
                              hipStream_t stream) {
    const int B = 8, S = 2048, D = 512;
    const float* x = (const float*)d_in[0];
    const float* W = (const float*)d_in[1];
    float* out = (float*)d_out;

    const size_t nx = (size_t)B * S * D;
    const size_t nw = (size_t)D * D;

    char* ws = (char*)d_ws;
    auto al = [](size_t v) { return (v + 255) & ~(size_t)255; };
    size_t off = 0;
    bf16* xb = (bf16*)(ws + off); off = al(off + nx * 2);          // x bf16 [B,S,D]
    bf16* xt = (bf16*)(ws + off); off = al(off + nx * 2);          // x^T bf16 [B,D,S]
    bf16* pb = (bf16*)(ws + off); off = al(off + nx * 2);          // proj bf16 [B,S,D]
    bf16* wt = (bf16*)(ws + off); off = al(off + nw * 2);          // W^T bf16 [D,D]
    float* rsum = (float*)(ws + off); off = al(off + (size_t)B * S * 4);
    bf16* sb = (bf16*)(ws + off);                                  // P_unnorm bf16
    const size_t full_need = off + (size_t)B * S * S * 2;
    const bool batched = (ws_size >= full_need);

    hipMemsetAsync(rsum, 0, (size_t)B * S * 4, stream);

    { dim3 g(S / 32, D / 32, B); cast_both<<<g, 256, 0, stream>>>(x, xb, xt, S, D); }
    { dim3 g(D / 32, D / 32, 1); cast_transpose<<<g, 256, 0, stream>>>(W, wt, D, D); }

    // proj: pb[BS,D] = xb @ wt^T   (grid 64x4 = 256 blocks)
    {
        dim3 g(B * S / 256, D / 128, 1);
        gemm256<0><<<g, 256, 0, stream>>>(xb, wt, (void*)pb, nullptr, B * S, D, D, 0, 0, 0, 0);
    }

    const long long sd = (long long)S * D;
    const long long ss = (long long)S * S;

    if (batched) {
        // P_un = exp(tanh(pb @ xb^T)) + rowsums   (grid 8x16x8 = 1024 blocks)
        dim3 g2(S / 256, S / 128, B);
        gemm256<1><<<g2, 256, 0, stream>>>(pb, xb, (void*)sb, rsum, S, S, D, sd, sd, ss, S);
        // out = (P_un @ xt^T) / rowsum            (grid 8x4x8 = 256 blocks)
        dim3 g4(S / 256, D / 128, B);
        gemm256<2><<<g4, 256, 0, stream>>>(sb, xt, (void*)out, rsum, S, D, S, ss, sd, sd, S);
    } else {
        for (int b = 0; b < B; ++b) {
            dim3 g2(S / 256, S / 128, 1);
            gemm256<1><<<g2, 256, 0, stream>>>(pb + (size_t)b * sd, xb + (size_t)b * sd,
                                               (void*)sb, rsum + (size_t)b * S, S, S, D, 0, 0, 0, 0);
            dim3 g4(S / 256, D / 128, 1);
            gemm256<2><<<g4, 256, 0, stream>>>(sb, xt + (size_t)b * sd,
                                               (void*)(out + (size_t)b * sd), rsum + (size_t)b * S,
                                               S, D, S, 0, 0, 0, 0);
        }
    }
}

// Round 7
// 218.534 us; speedup vs baseline: 1.2175x; 1.2175x over previous
//
#include <hip/hip_runtime.h>
#include <hip/hip_bf16.h>

typedef __bf16 bf16;
typedef __attribute__((ext_vector_type(8))) __bf16 bf16x8;
typedef __attribute__((ext_vector_type(4))) float floatx4;

// async global->LDS, 16B per lane. LDS dest is wave-uniform base + lane*16 (fixed by HW);
// we swizzle the GLOBAL source chunk so LDS frag reads are conflict-free (R5: conflicts 4.2M -> 0).
__device__ __forceinline__ void gl_lds16(const bf16* g, bf16* l) {
    __builtin_amdgcn_global_load_lds(
        (const __attribute__((address_space(1))) unsigned int*)g,
        (__attribute__((address_space(3))) unsigned int*)l,
        16, 0, 0);
}

// ---------------------------------------------------------------- x fp32 [R,C] -> xb bf16 [R,C] AND xt bf16 [C,R]
__global__ __launch_bounds__(256) void cast_both(const float* __restrict__ in,
                                                 bf16* __restrict__ outn,
                                                 bf16* __restrict__ outt,
                                                 int R, int C) {
    __shared__ float tile[32][33];
    const long long bz = blockIdx.z;
    in   += bz * (long long)R * C;
    outn += bz * (long long)R * C;
    outt += bz * (long long)R * C;
    const int r0 = blockIdx.x * 32, c0 = blockIdx.y * 32;
    const int tx = threadIdx.x & 31, ty = threadIdx.x >> 5;
#pragma unroll
    for (int i = 0; i < 32; i += 8) {
        float v = in[(long long)(r0 + ty + i) * C + (c0 + tx)];
        tile[ty + i][tx] = v;
        outn[(long long)(r0 + ty + i) * C + (c0 + tx)] = (bf16)v;
    }
    __syncthreads();
#pragma unroll
    for (int i = 0; i < 32; i += 8)
        outt[(long long)(c0 + ty + i) * R + (r0 + tx)] = (bf16)tile[tx][ty + i];
}

// ---------------------------------------------------------------- fp32 [R,C] -> bf16 [C,R] (for W)
__global__ __launch_bounds__(256) void cast_transpose(const float* __restrict__ in,
                                                      bf16* __restrict__ out,
                                                      int R, int C) {
    __shared__ float tile[32][33];
    const int r0 = blockIdx.x * 32, c0 = blockIdx.y * 32;
    const int tx = threadIdx.x & 31, ty = threadIdx.x >> 5;
#pragma unroll
    for (int i = 0; i < 32; i += 8)
        tile[ty + i][tx] = in[(long long)(r0 + ty + i) * C + (c0 + tx)];
    __syncthreads();
#pragma unroll
    for (int i = 0; i < 32; i += 8)
        out[(long long)(c0 + ty + i) * R + (r0 + tx)] = (bf16)tile[tx][ty + i];
}

// exp(tanh(x)) with 2 transcendentals instead of 3:
//   u = e^{2x}; t = tanh = 1 - 2/(u+1)  (exact saturation at +-1 for |x| large)
//   e^t on [-1,1] via degree-6 Taylor-Horner (rel err < 5.5e-4, well under bf16 storage error).
__device__ __forceinline__ float exp_tanh(float x) {
    float u = __expf(2.0f * x);
    float t = 1.0f - 2.0f / (u + 1.0f);
    float p = 1.0f / 720.0f;
    p = fmaf(p, t, 1.0f / 120.0f);
    p = fmaf(p, t, 1.0f / 24.0f);
    p = fmaf(p, t, 1.0f / 6.0f);
    p = fmaf(p, t, 0.5f);
    p = fmaf(p, t, 1.0f);
    p = fmaf(p, t, 1.0f);
    return p;
}

// ---------------------------------------------------------------- 128x128-tile NT GEMM, BK=64, swizzled
// C[M,N] = A[M,K]*B[N,K]^T; row-major bf16; K%64==0, M,N%128==0. 4 waves, 64x64 wave tiles
// (64 acc + ~80 arch VGPR -> 3 waves/SIMD; R6 showed 128x64 tiles kill occupancy).
// MODE 1: store bf16 exp(tanh(v)) + fp32 rowsum atomics  (scores)
// MODE 2: store fp32 v / rowsum[row]                      (PV, fused softmax divide)
template <int MODE>
__global__ __launch_bounds__(256) void gemm128(const bf16* __restrict__ A,
                                               const bf16* __restrict__ Bm,
                                               void* __restrict__ Cout,
                                               float* __restrict__ rowsum,
                                               int M, int N, int K,
                                               long long batchA, long long batchB,
                                               long long batchC, long long batchR) {
    const long long bz = blockIdx.z;
    A  += bz * batchA;
    Bm += bz * batchB;

    __shared__ bf16 As[128 * 64];   // 16 KB
    __shared__ bf16 Bs[128 * 64];   // 16 KB
    __shared__ float rs[128];       // MODE 2 only

    const int t    = threadIdx.x;
    const int lane = t & 63;
    const int wave = t >> 6;
    const int quad = lane >> 4;
    const int l16  = lane & 15;

    const int m0 = blockIdx.x * 128;
    const int n0 = blockIdx.y * 128;
    const int wm = (wave >> 1) * 64;
    const int wn = (wave & 1) * 64;

    floatx4 acc[4][4] = {};

    // staging: LDS slot (r, cl) holds global (r, cl ^ (r&7)); swizzle folded into base pointer.
    const int ra = t >> 3;
    const int ca = (((t & 7) ^ (ra & 7))) * 8;
    const long long rstep = 32LL * K;
    const bf16* Abase = A + (long long)(m0 + ra) * K + ca;
    const bf16* Bbase = Bm + (long long)(n0 + ra) * K + ca;

    const int cq0 = ((quad) ^ (l16 & 7)) * 8;
    const int cq1 = ((4 + quad) ^ (l16 & 7)) * 8;

    for (int k0 = 0; k0 < K; k0 += 64) {
#pragma unroll
        for (int i = 0; i < 4; ++i) {
            gl_lds16(Abase + k0 + i * rstep, &As[(t + 256 * i) * 8]);
            gl_lds16(Bbase + k0 + i * rstep, &Bs[(t + 256 * i) * 8]);
        }
        __syncthreads();

#pragma unroll
        for (int s = 0; s < 2; ++s) {
            const int cq = s ? cq1 : cq0;
            bf16x8 af[4], bfr[4];
#pragma unroll
            for (int i = 0; i < 4; ++i)
                af[i] = *(const bf16x8*)(&As[(wm + i * 16 + l16) * 64 + cq]);
#pragma unroll
            for (int j = 0; j < 4; ++j)
                bfr[j] = *(const bf16x8*)(&Bs[(wn + j * 16 + l16) * 64 + cq]);
#pragma unroll
            for (int i = 0; i < 4; ++i)
#pragma unroll
                for (int j = 0; j < 4; ++j)
                    acc[i][j] = __builtin_amdgcn_mfma_f32_16x16x32_bf16(af[i], bfr[j], acc[i][j], 0, 0, 0);
        }
        __syncthreads();
    }

    if (MODE == 1) {
        bf16* Cg = (bf16*)Cout + bz * batchC;
#pragma unroll
        for (int i = 0; i < 4; ++i)
#pragma unroll
            for (int r = 0; r < 4; ++r) {
                long long row = m0 + wm + i * 16 + quad * 4 + r;
                float s = 0.f;
#pragma unroll
                for (int j = 0; j < 4; ++j) {
                    float v = exp_tanh(acc[i][j][r]);
                    s += v;
                    Cg[row * (long long)N + (n0 + wn + j * 16 + l16)] = (bf16)v;
                }
#pragma unroll
                for (int msk = 1; msk < 16; msk <<= 1) s += __shfl_xor(s, msk);
                if (l16 == 0)
                    atomicAdd(&rowsum[bz * batchR + row], s);
            }
    } else {
        if (t < 128) rs[t] = rowsum[bz * batchR + m0 + t];
        __syncthreads();
        float* Og = (float*)Cout + bz * batchC;
#pragma unroll
        for (int i = 0; i < 4; ++i)
#pragma unroll
            for (int r = 0; r < 4; ++r) {
                int rl = wm + i * 16 + quad * 4 + r;
                float inv = 1.0f / rs[rl];
                long long row = m0 + rl;
#pragma unroll
                for (int j = 0; j < 4; ++j)
                    Og[row * (long long)N + (n0 + wn + j * 16 + l16)] = acc[i][j][r] * inv;
            }
    }
}

// ---------------------------------------------------------------- 64(M)x128(N) tile, BK=64, NT (proj)
__global__ __launch_bounds__(256) void gemm64_nt(const bf16* __restrict__ A,
                                                 const bf16* __restrict__ Bm,
                                                 bf16* __restrict__ Cout,
                                                 int M, int N, int K) {
    __shared__ bf16 As[64 * 64];    // 8 KB
    __shared__ bf16 Bs[128 * 64];   // 16 KB

    const int t    = threadIdx.x;
    const int lane = t & 63;
    const int wave = t >> 6;
    const int quad = lane >> 4;
    const int l16  = lane & 15;

    const int m0 = blockIdx.x * 64;
    const int n0 = blockIdx.y * 128;
    const int wn = wave * 32;

    floatx4 acc[4][2] = {};

    const int ra = t >> 3;
    const int ca = (((t & 7) ^ (ra & 7))) * 8;
    const long long rstep = 32LL * K;
    const bf16* Abase = A + (long long)(m0 + ra) * K + ca;
    const bf16* Bbase = Bm + (long long)(n0 + ra) * K + ca;

    const int cq0 = ((quad) ^ (l16 & 7)) * 8;
    const int cq1 = ((4 + quad) ^ (l16 & 7)) * 8;

    for (int k0 = 0; k0 < K; k0 += 64) {
#pragma unroll
        for (int i = 0; i < 2; ++i)
            gl_lds16(Abase + k0 + i * rstep, &As[(t + 256 * i) * 8]);
#pragma unroll
        for (int i = 0; i < 4; ++i)
            gl_lds16(Bbase + k0 + i * rstep, &Bs[(t + 256 * i) * 8]);
        __syncthreads();

#pragma unroll
        for (int s = 0; s < 2; ++s) {
            const int cq = s ? cq1 : cq0;
            bf16x8 af[4], bfr[2];
#pragma unroll
            for (int i = 0; i < 4; ++i)
                af[i] = *(const bf16x8*)(&As[(i * 16 + l16) * 64 + cq]);
#pragma unroll
            for (int j = 0; j < 2; ++j)
                bfr[j] = *(const bf16x8*)(&Bs[(wn + j * 16 + l16) * 64 + cq]);
#pragma unroll
            for (int i = 0; i < 4; ++i)
#pragma unroll
                for (int j = 0; j < 2; ++j)
                    acc[i][j] = __builtin_amdgcn_mfma_f32_16x16x32_bf16(af[i], bfr[j], acc[i][j], 0, 0, 0);
        }
        __syncthreads();
    }

    bf16* Cg = Cout;
#pragma unroll
    for (int i = 0; i < 4; ++i)
#pragma unroll
        for (int r = 0; r < 4; ++r) {
            long long row = m0 + i * 16 + quad * 4 + r;
#pragma unroll
            for (int j = 0; j < 2; ++j)
                Cg[row * (long long)N + (n0 + wn + j * 16 + l16)] = (bf16)acc[i][j][r];
        }
}

// ----------------------------------------------------------------
extern "C" void kernel_launch(void* const* d_in, const int* in_sizes, int n_in,
                              void* d_out, int out_size, void* d_ws, size_t ws_size,
                              hipStream_t stream) {
    const int B = 8, S = 2048, D = 512;
    const float* x = (const float*)d_in[0];
    const float* W = (const float*)d_in[1];
    float* out = (float*)d_out;

    const size_t nx = (size_t)B * S * D;
    const size_t nw = (size_t)D * D;

    char* ws = (char*)d_ws;
    auto al = [](size_t v) { return (v + 255) & ~(size_t)255; };
    size_t off = 0;
    bf16* xb = (bf16*)(ws + off); off = al(off + nx * 2);          // x bf16 [B,S,D]
    bf16* xt = (bf16*)(ws + off); off = al(off + nx * 2);          // x^T bf16 [B,D,S]
    bf16* pb = (bf16*)(ws + off); off = al(off + nx * 2);          // proj bf16 [B,S,D]
    bf16* wt = (bf16*)(ws + off); off = al(off + nw * 2);          // W^T bf16 [D,D]
    float* rsum = (float*)(ws + off); off = al(off + (size_t)B * S * 4);
    bf16* sb = (bf16*)(ws + off);                                  // P_unnorm bf16
    const size_t full_need = off + (size_t)B * S * S * 2;
    const bool batched = (ws_size >= full_need);

    hipMemsetAsync(rsum, 0, (size_t)B * S * 4, stream);

    { dim3 g(S / 32, D / 32, B); cast_both<<<g, 256, 0, stream>>>(x, xb, xt, S, D); }
    { dim3 g(D / 32, D / 32, 1); cast_transpose<<<g, 256, 0, stream>>>(W, wt, D, D); }

    // proj: pb[BS,D] = xb @ wt^T   (grid 256x4 = 1024 blocks)
    {
        dim3 g(B * S / 64, D / 128, 1);
        gemm64_nt<<<g, 256, 0, stream>>>(xb, wt, pb, B * S, D, D);
    }

    const long long sd = (long long)S * D;
    const long long ss = (long long)S * S;

    if (batched) {
        // P_un = exp(tanh(pb @ xb^T)) + rowsums   (grid 16x16x8 = 2048 blocks)
        dim3 g2(S / 128, S / 128, B);
        gemm128<1><<<g2, 256, 0, stream>>>(pb, xb, (void*)sb, rsum, S, S, D, sd, sd, ss, S);
        // out = (P_un @ xt^T) / rowsum            (grid 16x4x8 = 512 blocks)
        dim3 g4(S / 128, D / 128, B);
        gemm128<2><<<g4, 256, 0, stream>>>(sb, xt, (void*)out, rsum, S, D, S, ss, sd, sd, S);
    } else {
        for (int b = 0; b < B; ++b) {
            dim3 g2(S / 128, S / 128, 1);
            gemm128<1><<<g2, 256, 0, stream>>>(pb + (size_t)b * sd, xb + (size_t)b * sd,
                                               (void*)sb, rsum + (size_t)b * S, S, S, D, 0, 0, 0, 0);
            dim3 g4(S / 128, D / 128, 1);
            gemm128<2><<<g4, 256, 0, stream>>>(sb, xt + (size_t)b * sd,
                                               (void*)(out + (size_t)b * sd), rsum + (size_t)b * S,
                                               S, D, S, 0, 0, 0, 0);
        }
    }
}

// Round 9
// 209.454 us; speedup vs baseline: 1.2703x; 1.0434x over previous
//
#include <hip/hip_runtime.h>
#include <hip/hip_bf16.h>

typedef __bf16 bf16;
typedef __attribute__((ext_vector_type(8))) __bf16 bf16x8;
typedef __attribute__((ext_vector_type(4))) float floatx4;

#define NPART 16   // scores n-blocks per row (S/128)
#define NSLOT 32   // NPART * 2 wave-halves: each wave gets a private slot (no atomics, no races)

// async global->LDS, 16B per lane. LDS dest is wave-uniform base + lane*16 (fixed by HW);
// we swizzle the GLOBAL source chunk so LDS frag reads are conflict-free (R5: conflicts 4.2M -> 0).
__device__ __forceinline__ void gl_lds16(const bf16* g, bf16* l) {
    __builtin_amdgcn_global_load_lds(
        (const __attribute__((address_space(1))) unsigned int*)g,
        (__attribute__((address_space(3))) unsigned int*)l,
        16, 0, 0);
}

// 4(m) x 2(n) supertile swizzle: consecutive dispatch ids share A/B bands (L2 locality).
// Requires gridDim.x % 4 == 0 and gridDim.y % 2 == 0. Bijective on the grid.
__device__ __forceinline__ void swizzle_mn(int& bm, int& bn) {
    int gx = gridDim.x;
    int f  = blockIdx.y * gx + blockIdx.x;
    int st = f >> 3, r = f & 7;
    int mgroups = gx >> 2;
    bm = (st % mgroups) * 4 + (r & 3);
    bn = (st / mgroups) * 2 + (r >> 2);
}

// ---------------------------------------------------------------- x fp32 [R,C] -> xb bf16 [R,C] AND xt bf16 [C,R]
__global__ __launch_bounds__(256) void cast_both(const float* __restrict__ in,
                                                 bf16* __restrict__ outn,
                                                 bf16* __restrict__ outt,
                                                 int R, int C) {
    __shared__ float tile[32][33];
    const long long bz = blockIdx.z;
    in   += bz * (long long)R * C;
    outn += bz * (long long)R * C;
    outt += bz * (long long)R * C;
    const int r0 = blockIdx.x * 32, c0 = blockIdx.y * 32;
    const int tx = threadIdx.x & 31, ty = threadIdx.x >> 5;
#pragma unroll
    for (int i = 0; i < 32; i += 8) {
        float v = in[(long long)(r0 + ty + i) * C + (c0 + tx)];
        tile[ty + i][tx] = v;
        outn[(long long)(r0 + ty + i) * C + (c0 + tx)] = (bf16)v;
    }
    __syncthreads();
#pragma unroll
    for (int i = 0; i < 32; i += 8)
        outt[(long long)(c0 + ty + i) * R + (r0 + tx)] = (bf16)tile[tx][ty + i];
}

// ---------------------------------------------------------------- fp32 [R,C] -> bf16 [C,R] (for W)
__global__ __launch_bounds__(256) void cast_transpose(const float* __restrict__ in,
                                                      bf16* __restrict__ out,
                                                      int R, int C) {
    __shared__ float tile[32][33];
    const int r0 = blockIdx.x * 32, c0 = blockIdx.y * 32;
    const int tx = threadIdx.x & 31, ty = threadIdx.x >> 5;
#pragma unroll
    for (int i = 0; i < 32; i += 8)
        tile[ty + i][tx] = in[(long long)(r0 + ty + i) * C + (c0 + tx)];
    __syncthreads();
#pragma unroll
    for (int i = 0; i < 32; i += 8)
        out[(long long)(c0 + ty + i) * R + (r0 + tx)] = (bf16)tile[tx][ty + i];
}

// tanh via one exp + one rcp; exact saturation at +-1. (R7: poly outer-exp regressed; keep __expf.)
__device__ __forceinline__ float fast_tanh(float v) {
    float e = __expf(2.0f * v);
    return 1.0f - 2.0f / (e + 1.0f);
}

// ---------------------------------------------------------------- 128x128-tile NT GEMM, BK=64, swizzled
// C[M,N] = A[M,K]*B[N,K]^T; row-major bf16; K%64==0, M,N%128==0. 4 waves, 64x64 wave tiles
// (64 acc + ~80 arch VGPR -> 3 waves/SIMD; R6: bigger wave tiles -> 1 wave/SIMD, 1.6x slower).
// MODE 1 (scores): store bf16 exp(tanh(v)); per-(row, n-block, wave-half) rowsum partials.
//                  R8 bug fixed: the two wn-halves of a row now write DISTINCT slots.
// MODE 2 (PV):     prologue reduces NSLOT partials per row; store fp32 v * invRowsum.
template <int MODE>
__global__ __launch_bounds__(256) void gemm128(const bf16* __restrict__ A,
                                               const bf16* __restrict__ Bm,
                                               void* __restrict__ Cout,
                                               float* __restrict__ rpart,
                                               int M, int N, int K,
                                               long long batchA, long long batchB,
                                               long long batchC, long long batchR) {
    const long long bz = blockIdx.z;
    A  += bz * batchA;
    Bm += bz * batchB;

    __shared__ bf16 As[128 * 64];   // 16 KB
    __shared__ bf16 Bs[128 * 64];   // 16 KB
    __shared__ float rs[128];       // MODE 2 only

    const int t    = threadIdx.x;
    const int lane = t & 63;
    const int wave = t >> 6;
    const int quad = lane >> 4;
    const int l16  = lane & 15;

    int bm, bn;
    swizzle_mn(bm, bn);
    const int m0 = bm * 128;
    const int n0 = bn * 128;
    const int wm = (wave >> 1) * 64;
    const int wn = (wave & 1) * 64;

    floatx4 acc[4][4] = {};

    // staging: LDS slot (r, cl) holds global (r, cl ^ (r&7)); swizzle folded into base pointer.
    const int ra = t >> 3;
    const int ca = (((t & 7) ^ (ra & 7))) * 8;
    const long long rstep = 32LL * K;
    const bf16* Abase = A + (long long)(m0 + ra) * K + ca;
    const bf16* Bbase = Bm + (long long)(n0 + ra) * K + ca;

    const int cq0 = ((quad) ^ (l16 & 7)) * 8;
    const int cq1 = ((4 + quad) ^ (l16 & 7)) * 8;

    // MODE 2: fold softmax denominators (sum of NSLOT partials per row) into rs[] up front.
    if (MODE == 2) {
        if (t < 128) {
            const float* pp = rpart + (bz * batchR + m0 + t) * NSLOT;
            float s = 0.f;
#pragma unroll
            for (int c = 0; c < NSLOT / 4; ++c) {
                float4 p = ((const float4*)pp)[c];
                s += (p.x + p.y) + (p.z + p.w);
            }
            rs[t] = 1.0f / s;
        }
        // rs is read only after the K-loop's final __syncthreads -> ordering is safe
    }

    for (int k0 = 0; k0 < K; k0 += 64) {
#pragma unroll
        for (int i = 0; i < 4; ++i) {
            gl_lds16(Abase + k0 + i * rstep, &As[(t + 256 * i) * 8]);
            gl_lds16(Bbase + k0 + i * rstep, &Bs[(t + 256 * i) * 8]);
        }
        __syncthreads();

#pragma unroll
        for (int s = 0; s < 2; ++s) {
            const int cq = s ? cq1 : cq0;
            bf16x8 af[4], bfr[4];
#pragma unroll
            for (int i = 0; i < 4; ++i)
                af[i] = *(const bf16x8*)(&As[(wm + i * 16 + l16) * 64 + cq]);
#pragma unroll
            for (int j = 0; j < 4; ++j)
                bfr[j] = *(const bf16x8*)(&Bs[(wn + j * 16 + l16) * 64 + cq]);
#pragma unroll
            for (int i = 0; i < 4; ++i)
#pragma unroll
                for (int j = 0; j < 4; ++j)
                    acc[i][j] = __builtin_amdgcn_mfma_f32_16x16x32_bf16(af[i], bfr[j], acc[i][j], 0, 0, 0);
        }
        __syncthreads();
    }

    if (MODE == 1) {
        bf16* Cg = (bf16*)Cout + bz * batchC;
        const int slot = bn * 2 + (wave & 1);   // private slot per (n-block, wave-half)
#pragma unroll
        for (int i = 0; i < 4; ++i)
#pragma unroll
            for (int r = 0; r < 4; ++r) {
                long long row = m0 + wm + i * 16 + quad * 4 + r;
                float s = 0.f;
#pragma unroll
                for (int j = 0; j < 4; ++j) {
                    float v = __expf(fast_tanh(acc[i][j][r]));
                    s += v;
                    Cg[row * (long long)N + (n0 + wn + j * 16 + l16)] = (bf16)v;
                }
#pragma unroll
                for (int msk = 1; msk < 16; msk <<= 1) s += __shfl_xor(s, msk);
                if (l16 == 0)
                    rpart[(bz * batchR + row) * NSLOT + slot] = s;   // plain store, race-free
            }
    } else {
        float* Og = (float*)Cout + bz * batchC;
#pragma unroll
        for (int i = 0; i < 4; ++i)
#pragma unroll
            for (int r = 0; r < 4; ++r) {
                int rl = wm + i * 16 + quad * 4 + r;
                float inv = rs[rl];
                long long row = m0 + rl;
#pragma unroll
                for (int j = 0; j < 4; ++j)
                    Og[row * (long long)N + (n0 + wn + j * 16 + l16)] = acc[i][j][r] * inv;
            }
    }
}

// ---------------------------------------------------------------- 64(M)x128(N) tile, BK=64, NT (proj)
__global__ __launch_bounds__(256) void gemm64_nt(const bf16* __restrict__ A,
                                                 const bf16* __restrict__ Bm,
                                                 bf16* __restrict__ Cout,
                                                 int M, int N, int K) {
    __shared__ bf16 As[64 * 64];    // 8 KB
    __shared__ bf16 Bs[128 * 64];   // 16 KB

    const int t    = threadIdx.x;
    const int lane = t & 63;
    const int wave = t >> 6;
    const int quad = lane >> 4;
    const int l16  = lane & 15;

    const int m0 = blockIdx.x * 64;
    const int n0 = blockIdx.y * 128;
    const int wn = wave * 32;

    floatx4 acc[4][2] = {};

    const int ra = t >> 3;
    const int ca = (((t & 7) ^ (ra & 7))) * 8;
    const long long rstep = 32LL * K;
    const bf16* Abase = A + (long long)(m0 + ra) * K + ca;
    const bf16* Bbase = Bm + (long long)(n0 + ra) * K + ca;

    const int cq0 = ((quad) ^ (l16 & 7)) * 8;
    const int cq1 = ((4 + quad) ^ (l16 & 7)) * 8;

    for (int k0 = 0; k0 < K; k0 += 64) {
#pragma unroll
        for (int i = 0; i < 2; ++i)
            gl_lds16(Abase + k0 + i * rstep, &As[(t + 256 * i) * 8]);
#pragma unroll
        for (int i = 0; i < 4; ++i)
            gl_lds16(Bbase + k0 + i * rstep, &Bs[(t + 256 * i) * 8]);
        __syncthreads();

#pragma unroll
        for (int s = 0; s < 2; ++s) {
            const int cq = s ? cq1 : cq0;
            bf16x8 af[4], bfr[2];
#pragma unroll
            for (int i = 0; i < 4; ++i)
                af[i] = *(const bf16x8*)(&As[(i * 16 + l16) * 64 + cq]);
#pragma unroll
            for (int j = 0; j < 2; ++j)
                bfr[j] = *(const bf16x8*)(&Bs[(wn + j * 16 + l16) * 64 + cq]);
#pragma unroll
            for (int i = 0; i < 4; ++i)
#pragma unroll
                for (int j = 0; j < 2; ++j)
                    acc[i][j] = __builtin_amdgcn_mfma_f32_16x16x32_bf16(af[i], bfr[j], acc[i][j], 0, 0, 0);
        }
        __syncthreads();
    }

#pragma unroll
    for (int i = 0; i < 4; ++i)
#pragma unroll
        for (int r = 0; r < 4; ++r) {
            long long row = m0 + i * 16 + quad * 4 + r;
#pragma unroll
            for (int j = 0; j < 2; ++j)
                Cout[row * (long long)N + (n0 + wn + j * 16 + l16)] = (bf16)acc[i][j][r];
        }
}

// ----------------------------------------------------------------
extern "C" void kernel_launch(void* const* d_in, const int* in_sizes, int n_in,
                              void* d_out, int out_size, void* d_ws, size_t ws_size,
                              hipStream_t stream) {
    const int B = 8, S = 2048, D = 512;
    const float* x = (const float*)d_in[0];
    const float* W = (const float*)d_in[1];
    float* out = (float*)d_out;

    const size_t nx = (size_t)B * S * D;
    const size_t nw = (size_t)D * D;

    char* ws = (char*)d_ws;
    auto al = [](size_t v) { return (v + 255) & ~(size_t)255; };
    size_t off = 0;
    bf16* xb = (bf16*)(ws + off); off = al(off + nx * 2);          // x bf16 [B,S,D]
    bf16* xt = (bf16*)(ws + off); off = al(off + nx * 2);          // x^T bf16 [B,D,S]
    bf16* pb = (bf16*)(ws + off); off = al(off + nx * 2);          // proj bf16 [B,S,D]
    bf16* wt = (bf16*)(ws + off); off = al(off + nw * 2);          // W^T bf16 [D,D]
    float* rpart = (float*)(ws + off); off = al(off + (size_t)B * S * NSLOT * 4);  // rowsum partials
    bf16* sb = (bf16*)(ws + off);                                  // P_unnorm bf16
    const size_t full_need = off + (size_t)B * S * S * 2;
    const bool batched = (ws_size >= full_need);

    { dim3 g(S / 32, D / 32, B); cast_both<<<g, 256, 0, stream>>>(x, xb, xt, S, D); }
    { dim3 g(D / 32, D / 32, 1); cast_transpose<<<g, 256, 0, stream>>>(W, wt, D, D); }

    // proj: pb[BS,D] = xb @ wt^T   (grid 256x4 = 1024 blocks)
    {
        dim3 g(B * S / 64, D / 128, 1);
        gemm64_nt<<<g, 256, 0, stream>>>(xb, wt, pb, B * S, D, D);
    }

    const long long sd = (long long)S * D;
    const long long ss = (long long)S * S;

    if (batched) {
        // P_un = exp(tanh(pb @ xb^T)), rowsum partials   (grid 16x16x8)
        dim3 g2(S / 128, S / 128, B);
        gemm128<1><<<g2, 256, 0, stream>>>(pb, xb, (void*)sb, rpart, S, S, D, sd, sd, ss, S);
        // out = (P_un @ xt^T) * invRowsum                (grid 16x4x8)
        dim3 g4(S / 128, D / 128, B);
        gemm128<2><<<g4, 256, 0, stream>>>(sb, xt, (void*)out, rpart, S, D, S, ss, sd, sd, S);
    } else {
        for (int b = 0; b < B; ++b) {
            dim3 g2(S / 128, S / 128, 1);
            gemm128<1><<<g2, 256, 0, stream>>>(pb + (size_t)b * sd, xb + (size_t)b * sd,
                                               (void*)sb, rpart + (size_t)b * S * NSLOT,
                                               S, S, D, 0, 0, 0, S);
            dim3 g4(S / 128, D / 128, 1);
            gemm128<2><<<g4, 256, 0, stream>>>(sb, xt + (size_t)b * sd,
                                               (void*)(out + (size_t)b * sd), rpart + (size_t)b * S * NSLOT,
                                               S, D, S, 0, 0, 0, S);
        }
    }
}